// Round 2
// baseline (2946.420 us; speedup 1.0000x reference)
//
#include <hip/hip_runtime.h>
#include <hip/hip_bf16.h>
#include <type_traits>

// Problem constants
#define T_STEPS 4
#define B_SZ 8
#define C_IN 512
#define CH 2048
#define N_SP 1024          // H*W
#define NHEADS 8
#define HDIM 64
#define S_C ((size_t)B_SZ * C_IN * N_SP)    // 4,194,304 elems per timestep

typedef unsigned char u8;

// ---------------------------------------------------------------------------
// LIF on input x -> uint8 spikes. v <- v + (x-v)/2 ; s = H(v-0.5) ; reset.
// ---------------------------------------------------------------------------
__global__ __launch_bounds__(256) void lif_x_kernel(const float* __restrict__ in,
                                                    u8* __restrict__ out)
{
    size_t i = (size_t)blockIdx.x * 256 + threadIdx.x;
    float v = 0.0f;
    #pragma unroll
    for (int t = 0; t < T_STEPS; ++t) {
        float x = in[(size_t)t * S_C + i];
        v += (x - v) * 0.5f;
        u8 s = (v >= 0.5f) ? 1 : 0;
        out[(size_t)t * S_C + i] = s;
        v = s ? 0.0f : v;
    }
}

// ---------------------------------------------------------------------------
// Fused batched GEMM + BN (+bias) with LIF looped over T inside the block.
//   acc[co,n] = sum_k W[co,k] * X[t,b,k,n]   (X optionally masked by kvs[t,b,k])
//   y = acc*scale + shift
// MODE 0: LIF -> uint8 spike out
// MODE 1: (proj) y + res -> fp32 out
// MODE 2: (fc2)  LIF -> spike + res -> fp32 out
// Tile 64(co) x 64(n), BK=16, 256 threads, 4x4 per thread. grid.z = b in [0,8).
// ---------------------------------------------------------------------------
template<int MODE, bool BIAS, typename InT>
__global__ __launch_bounds__(256) void gemm_fused(
    const InT* __restrict__ X,     // [T,B,K,N]
    const float* __restrict__ W,   // [Co,K]
    const float* __restrict__ bnp, // [4,Co]
    const float* __restrict__ bias,// [Co]
    const float* __restrict__ kvs, // [T*B,K]  (MODE 1 only)
    const float* res,              // [T,B,Co,N] (MODE 1/2) -- may alias Y
    void* Yv,
    int K, int Co)
{
    const int N = N_SP;
    const int b = blockIdx.z;
    const int coBase = blockIdx.y * 64;
    const int nBase = blockIdx.x * 64;
    const int tid = threadIdx.x;
    const int tx = tid & 15, ty = tid >> 4;

    __shared__ float As[16][68];   // [k][co]
    __shared__ float Bs[16][68];   // [k][n]

    const int arow = tid >> 2, ak0 = (tid & 3) * 4;   // A loader
    const int brow = tid >> 4, bn0 = (tid & 15) * 4;  // B loader

    // BN constants for this thread's 4 output rows
    float scale[4], shift[4];
    #pragma unroll
    for (int i = 0; i < 4; ++i) {
        const int co = coBase + ty * 4 + i;
        const float g  = bnp[co];
        const float be = bnp[Co + co];
        const float mn = bnp[2 * Co + co];
        const float vr = bnp[3 * Co + co];
        scale[i] = g / sqrtf(vr + 1e-5f);
        shift[i] = be - mn * scale[i];
        if (BIAS) shift[i] += bias[co] * scale[i];
    }

    float vst[4][4] = {};   // LIF membrane state (MODE 0/2)

    for (int t = 0; t < T_STEPS; ++t) {
        const size_t tb = (size_t)(t * B_SZ + b);
        const InT* Xb = X + tb * (size_t)K * N;
        float acc[4][4] = {};

        for (int k0 = 0; k0 < K; k0 += 16) {
            float4 av = *reinterpret_cast<const float4*>(
                W + (size_t)(coBase + arow) * K + k0 + ak0);
            As[ak0 + 0][arow] = av.x;
            As[ak0 + 1][arow] = av.y;
            As[ak0 + 2][arow] = av.z;
            As[ak0 + 3][arow] = av.w;

            float4 bv;
            if constexpr (std::is_same<InT, u8>::value) {
                uchar4 u = *reinterpret_cast<const uchar4*>(
                    Xb + (size_t)(k0 + brow) * N + nBase + bn0);
                bv = make_float4((float)u.x, (float)u.y, (float)u.z, (float)u.w);
            } else {
                bv = *reinterpret_cast<const float4*>(
                    Xb + (size_t)(k0 + brow) * N + nBase + bn0);
            }
            if constexpr (MODE == 1) {
                float m = kvs[tb * K + k0 + brow];
                bv.x *= m; bv.y *= m; bv.z *= m; bv.w *= m;
            }
            *reinterpret_cast<float4*>(&Bs[brow][bn0]) = bv;

            __syncthreads();
            #pragma unroll
            for (int kk = 0; kk < 16; ++kk) {
                float4 a = *reinterpret_cast<const float4*>(&As[kk][ty * 4]);
                float4 bq = *reinterpret_cast<const float4*>(&Bs[kk][tx * 4]);
                float aa[4] = {a.x, a.y, a.z, a.w};
                float bb[4] = {bq.x, bq.y, bq.z, bq.w};
                #pragma unroll
                for (int i = 0; i < 4; ++i)
                    #pragma unroll
                    for (int j = 0; j < 4; ++j)
                        acc[i][j] += aa[i] * bb[j];
            }
            __syncthreads();
        }

        // epilogue for this timestep
        #pragma unroll
        for (int i = 0; i < 4; ++i) {
            const int co = coBase + ty * 4 + i;
            const size_t rowOff = (tb * Co + co) * (size_t)N + nBase + tx * 4;
            if constexpr (MODE == 0) {
                u8 sj[4];
                #pragma unroll
                for (int j = 0; j < 4; ++j) {
                    const float y = acc[i][j] * scale[i] + shift[i];
                    float v = vst[i][j];
                    v += (y - v) * 0.5f;
                    const u8 s = (v >= 0.5f) ? 1 : 0;
                    sj[j] = s;
                    vst[i][j] = s ? 0.0f : v;
                }
                *reinterpret_cast<uchar4*>((u8*)Yv + rowOff) =
                    make_uchar4(sj[0], sj[1], sj[2], sj[3]);
            } else if constexpr (MODE == 1) {
                const float4 r = *reinterpret_cast<const float4*>(res + rowOff);
                float4 o;
                o.x = acc[i][0] * scale[i] + shift[i] + r.x;
                o.y = acc[i][1] * scale[i] + shift[i] + r.y;
                o.z = acc[i][2] * scale[i] + shift[i] + r.z;
                o.w = acc[i][3] * scale[i] + shift[i] + r.w;
                *reinterpret_cast<float4*>((float*)Yv + rowOff) = o;
            } else {
                const float4 r = *reinterpret_cast<const float4*>(res + rowOff);
                float o[4] = {r.x, r.y, r.z, r.w};
                #pragma unroll
                for (int j = 0; j < 4; ++j) {
                    const float y = acc[i][j] * scale[i] + shift[i];
                    float v = vst[i][j];
                    v += (y - v) * 0.5f;
                    const u8 s = (v >= 0.5f) ? 1 : 0;
                    o[j] += s ? 1.0f : 0.0f;
                    vst[i][j] = s ? 0.0f : v;
                }
                *reinterpret_cast<float4*>((float*)Yv + rowOff) =
                    make_float4(o[0], o[1], o[2], o[3]);
            }
        }
    }
}

// ---------------------------------------------------------------------------
// kv_raw[t,b,c] = sum_n k*v  (binary AND-count); one 64-lane wave per row
// ---------------------------------------------------------------------------
__global__ __launch_bounds__(256) void kv_reduce(const u8* __restrict__ ks,
                                                 const u8* __restrict__ vs,
                                                 float* __restrict__ kv)
{
    const int row = blockIdx.x * 4 + (threadIdx.x >> 6);  // [0, T*B*C)
    const int lane = threadIdx.x & 63;
    const u8* kp = ks + (size_t)row * N_SP;
    const u8* vp = vs + (size_t)row * N_SP;
    int acc = 0;
    #pragma unroll
    for (int n = 0; n < N_SP; n += 256) {
        uchar4 a = *reinterpret_cast<const uchar4*>(kp + n + lane * 4);
        uchar4 c = *reinterpret_cast<const uchar4*>(vp + n + lane * 4);
        acc += (a.x & c.x) + (a.y & c.y) + (a.z & c.z) + (a.w & c.w);
    }
    #pragma unroll
    for (int off = 32; off; off >>= 1) acc += __shfl_down(acc, off, 64);
    if (lane == 0) kv[row] = (float)acc;
}

// ---------------------------------------------------------------------------
// talking heads (8x8 over heads) + LIF -> kvs[t,b,c] in {0,1} (fp32)
// ---------------------------------------------------------------------------
__global__ __launch_bounds__(256) void th_lif(const float* __restrict__ kvraw,
                                              const float* __restrict__ th,
                                              float* __restrict__ kvs)
{
    const int i = blockIdx.x * 256 + threadIdx.x;   // [0, B*C)
    const int b = i >> 9;
    const int c = i & 511;
    const int g = c >> 6;
    const int dd = c & 63;
    float v = 0.0f;
    #pragma unroll
    for (int t = 0; t < T_STEPS; ++t) {
        const float* base = kvraw + ((size_t)t * B_SZ + b) * C_IN;
        float x = 0.0f;
        #pragma unroll
        for (int hh = 0; hh < NHEADS; ++hh)
            x += base[hh * HDIM + dd] * th[g * NHEADS + hh];
        v += (x - v) * 0.5f;
        const float s = (v >= 0.5f) ? 1.0f : 0.0f;
        kvs[((size_t)t * B_SZ + b) * C_IN + c] = s;
        v = (s != 0.0f) ? 0.0f : v;
    }
}

extern "C" void kernel_launch(void* const* d_in, const int* in_sizes, int n_in,
                              void* d_out, int out_size, void* d_ws, size_t ws_size,
                              hipStream_t stream)
{
    const float* x       = (const float*)d_in[0];
    const float* q_w     = (const float*)d_in[1];
    const float* q_bn    = (const float*)d_in[2];
    const float* k_w     = (const float*)d_in[3];
    const float* k_bn    = (const float*)d_in[4];
    const float* v_w     = (const float*)d_in[5];
    const float* v_bn    = (const float*)d_in[6];
    const float* th_w    = (const float*)d_in[7];
    const float* proj_w  = (const float*)d_in[8];
    const float* proj_b  = (const float*)d_in[9];
    const float* proj_bn = (const float*)d_in[10];
    const float* fc1_w   = (const float*)d_in[11];
    const float* fc1_b   = (const float*)d_in[12];
    const float* fc1_bn  = (const float*)d_in[13];
    const float* fc2_w   = (const float*)d_in[14];
    const float* fc2_b   = (const float*)d_in[15];
    const float* fc2_bn  = (const float*)d_in[16];
    float* out = (float*)d_out;

    // workspace layout: total 67,239,936 bytes (~64.1 MiB)
    const size_t SLOT = (size_t)T_STEPS * S_C;    // 16,777,216 bytes per u8 slot
    u8* sp  = (u8*)d_ws;
    u8* xs  = sp;                 // [T,B,C,N] u8 spikes
    u8* qs  = sp + SLOT;
    u8* ks  = sp + 2 * SLOT;
    u8* vs  = sp + 3 * SLOT;
    u8* hdn = sp;                 // [T,B,Ch,N] u8, reuses xs..vs (all dead by fc1)
    float* kvraw = (float*)(sp + 4 * SLOT);               // [T*B,C]
    float* kvs   = kvraw + (size_t)T_STEPS * B_SZ * C_IN; // [T*B,C]
    // xout lives in d_out (proj writes it; fc2 consumes it in place)

    // 1. xs = lif(x)
    lif_x_kernel<<<(int)(S_C / 256), 256, 0, stream>>>(x, xs);

    // 2-4. q/k/v = lif(bn(conv(xs)))  -> uint8 spikes
    dim3 gC(16, 8, 8);
    gemm_fused<0, false, u8><<<gC, 256, 0, stream>>>(xs, q_w, q_bn, nullptr, nullptr, nullptr, qs, C_IN, C_IN);
    gemm_fused<0, false, u8><<<gC, 256, 0, stream>>>(xs, k_w, k_bn, nullptr, nullptr, nullptr, ks, C_IN, C_IN);
    gemm_fused<0, false, u8><<<gC, 256, 0, stream>>>(xs, v_w, v_bn, nullptr, nullptr, nullptr, vs, C_IN, C_IN);

    // 5. kv_raw = rowwise dot(k, v) over N
    kv_reduce<<<(T_STEPS * B_SZ * C_IN) / 4, 256, 0, stream>>>(ks, vs, kvraw);

    // 6. talking heads + lif -> kvs (binary fp32)
    th_lif<<<(B_SZ * C_IN) / 256, 256, 0, stream>>>(kvraw, th_w, kvs);

    // 7. xout = bn(proj(q * kvs) + proj_b) + x   -> d_out
    gemm_fused<1, true, u8><<<gC, 256, 0, stream>>>(qs, proj_w, proj_bn, proj_b, kvs, x, out, C_IN, C_IN);

    // 8. hdn = lif(bn(fc1(xout) + fc1_b))  -> uint8 spikes
    dim3 gCh(16, 32, 8);
    gemm_fused<0, true, float><<<gCh, 256, 0, stream>>>(out, fc1_w, fc1_bn, fc1_b, nullptr, nullptr, hdn, C_IN, CH);

    // 9. out = lif(bn(fc2(hdn) + fc2_b)) + xout   (in place on d_out)
    gemm_fused<2, true, u8><<<gC, 256, 0, stream>>>(hdn, fc2_w, fc2_bn, fc2_b, nullptr, out, out, CH, C_IN);
}